// Round 7
// baseline (623.744 us; speedup 1.0000x reference)
//
#include <hip/hip_runtime.h>
#include <math.h>

// VanillaRNN via MFMA: B=1024, T=512, I=64, H=128, O=10, fp32 in/out.
// Block = 16 batch rows (64 blocks), now 512 threads = 8 WAVES (2 per SIMD).
// ROUND 7 KEY CHANGE: round-6 ran 1 wave/SIMD -> ~1100 cyc/step of exposed
// latency with all pipes idle (MfmaUtil 2.6%, VALUBusy 8.4%). Splitting N
// 8 ways (each wave owns ONE 16-col N-tile, 6 MFMAs/step) puts 2 co-resident
// waves on every SIMD so ds_read/MFMA/tanh latencies interleave, and halves
// the per-wave tail (4 tanh + 4 ds_write vs 8). MFMA pipe time per SIMD
// unchanged (2 waves x 6 = 12 MFMAs).
// Kept from earlier rounds: LDS-only barrier (no vmcnt drain), depth-2 x
// prefetch, asm-pinned B-frags (anti-remat), PITCH=136 bf16 ping-pong h.

#define T_STEPS 512
#define I_DIM   64
#define H_DIM   128
#define O_DIM   10
#define BT      16            // batch rows per block
#define PITCH   136           // bf16 elements per h row
#define NTHR    512

typedef short  bf16x8 __attribute__((ext_vector_type(8)));
typedef float  f32x4  __attribute__((ext_vector_type(4)));

static __device__ inline short f2bf(float f) {
    union { float f; unsigned u; } v; v.f = f;
    unsigned r = v.u + 0x7FFFu + ((v.u >> 16) & 1u);   // round-to-nearest-even
    return (short)(r >> 16);
}
static __device__ inline float bf2f(short s) {
    union { unsigned u; float f; } v; v.u = ((unsigned)(unsigned short)s) << 16;
    return v.f;
}

// Barrier that does NOT drain vmcnt: h handoff only needs LDS ops complete.
// In-flight global x prefetches legally cross (write only private VGPRs).
static __device__ inline void lds_barrier() {
    asm volatile("s_waitcnt lgkmcnt(0)\n\ts_barrier" ::: "memory");
}

// One RNN step. XR holds raw fp32 x_t (loaded 2 steps ago); after converting
// it to A-frags we reuse XR to issue the load for t+2.
#define RNN_STEP(t, XR)                                                         \
    {                                                                           \
        const int p = (t) & 1;                                                  \
        /* h_t A-frags from LDS first: latency overlaps the x convert below. */ \
        const short* hb = hbuf[p] + c * PITCH + q * 8;                          \
        bf16x8 Ah0 = *(const bf16x8*)(hb +  0);                                 \
        bf16x8 Ah1 = *(const bf16x8*)(hb + 32);                                 \
        bf16x8 Ah2 = *(const bf16x8*)(hb + 64);                                 \
        bf16x8 Ah3 = *(const bf16x8*)(hb + 96);                                 \
        bf16x8 Ax0, Ax1;                                                        \
        Ax0[0]=f2bf(XR[0].x); Ax0[1]=f2bf(XR[0].y); Ax0[2]=f2bf(XR[0].z); Ax0[3]=f2bf(XR[0].w); \
        Ax0[4]=f2bf(XR[1].x); Ax0[5]=f2bf(XR[1].y); Ax0[6]=f2bf(XR[1].z); Ax0[7]=f2bf(XR[1].w); \
        Ax1[0]=f2bf(XR[2].x); Ax1[1]=f2bf(XR[2].y); Ax1[2]=f2bf(XR[2].z); Ax1[3]=f2bf(XR[2].w); \
        Ax1[4]=f2bf(XR[3].x); Ax1[5]=f2bf(XR[3].y); Ax1[6]=f2bf(XR[3].z); Ax1[7]=f2bf(XR[3].w); \
        {                                                                       \
            const int tn = ((t) + 2 < T_STEPS) ? (t) + 2 : T_STEPS - 1;         \
            const float* pn = xrow + (size_t)tn * I_DIM;                        \
            XR[0] = *(const float4*)(pn +      q * 8);                          \
            XR[1] = *(const float4*)(pn +      q * 8 + 4);                      \
            XR[2] = *(const float4*)(pn + 32 + q * 8);                          \
            XR[3] = *(const float4*)(pn + 32 + q * 8 + 4);                      \
        }                                                                       \
        /* 6 MFMAs in 2 independent chains of 3. */                             \
        f32x4 Ca = {0.f,0.f,0.f,0.f}, Cb = {0.f,0.f,0.f,0.f};                   \
        Ca = __builtin_amdgcn_mfma_f32_16x16x32_bf16(Ax0, __builtin_bit_cast(bf16x8, Bw[4]), Ca, 0, 0, 0); \
        Cb = __builtin_amdgcn_mfma_f32_16x16x32_bf16(Ax1, __builtin_bit_cast(bf16x8, Bw[5]), Cb, 0, 0, 0); \
        Ca = __builtin_amdgcn_mfma_f32_16x16x32_bf16(Ah0, __builtin_bit_cast(bf16x8, Bw[0]), Ca, 0, 0, 0); \
        Cb = __builtin_amdgcn_mfma_f32_16x16x32_bf16(Ah1, __builtin_bit_cast(bf16x8, Bw[1]), Cb, 0, 0, 0); \
        Ca = __builtin_amdgcn_mfma_f32_16x16x32_bf16(Ah2, __builtin_bit_cast(bf16x8, Bw[2]), Ca, 0, 0, 0); \
        Cb = __builtin_amdgcn_mfma_f32_16x16x32_bf16(Ah3, __builtin_bit_cast(bf16x8, Bw[3]), Cb, 0, 0, 0); \
        const f32x4 C = Ca + Cb;                                                \
        /* tanh + cvt + scatter into h_{t+1}. C/D: row m = 4q+r, col n. */      \
        short* hw = hbuf[1 - p];                                                \
        _Pragma("unroll")                                                       \
        for (int r = 0; r < 4; ++r) {                                           \
            const int m = q * 4 + r;                                            \
            float s0 = C[r] + bias;                                             \
            float e0 = __builtin_amdgcn_exp2f(s0 * 2.885390081777926825f);      \
            float h0 = fmaf(-2.0f, __builtin_amdgcn_rcpf(e0 + 1.0f), 1.0f);     \
            hw[m * PITCH + w * 16 + c] = f2bf(h0);                              \
        }                                                                       \
        lds_barrier();   /* LDS-only: x prefetches stay in flight */            \
    }

__global__ __launch_bounds__(NTHR)
__attribute__((amdgpu_waves_per_eu(1, 2)))
void rnn_mfma_kernel(
    const float* __restrict__ x,      // [B, T, I]
    const float* __restrict__ W_hx,   // [H, I]
    const float* __restrict__ W_hh,   // [H, H]
    const float* __restrict__ b_hh,   // [H]
    const float* __restrict__ W_ph,   // [O, H]
    const float* __restrict__ b_ph,   // [O]
    float* __restrict__ out)          // [B, O]
{
    const int b0   = blockIdx.x * BT;
    const int tid  = threadIdx.x;
    const int w    = tid >> 6;        // wave 0..7 -> N cols [16w, 16w+16)
    const int lane = tid & 63;
    const int c    = lane & 15;       // n-col within tile; batch-row for A reads
    const int q    = lane >> 4;       // quad

    __shared__ short hbuf[2][BT * PITCH];   // bf16 h, ping-pong

    // ---- Preload W_cat^T B-fragments: Bw[kt], kt 0..3 = W_hh, 4..5 = W_hx.
    // B-frag: lane holds B[k=8q+j][n=c] = W_cat[n][kt*32+8q+j], j=0..7.
    int4 Bw[6];
    {
        const int n = w * 16 + c;
        #pragma unroll
        for (int kt = 0; kt < 6; ++kt) {
            const float* src = (kt < 4) ? (W_hh + n * H_DIM + kt * 32 + q * 8)
                                        : (W_hx + n * I_DIM + (kt - 4) * 32 + q * 8);
            short e[8];
            #pragma unroll
            for (int j = 0; j < 8; ++j) e[j] = f2bf(src[j]);
            Bw[kt].x = ((int)(unsigned short)e[0]) | ((int)(unsigned short)e[1] << 16);
            Bw[kt].y = ((int)(unsigned short)e[2]) | ((int)(unsigned short)e[3] << 16);
            Bw[kt].z = ((int)(unsigned short)e[4]) | ((int)(unsigned short)e[5] << 16);
            Bw[kt].w = ((int)(unsigned short)e[6]) | ((int)(unsigned short)e[7] << 16);
        }
    }
    // Pin: forbid remat/sink of the weight loads into the time loop.
    #pragma unroll
    for (int kt = 0; kt < 6; ++kt)
        asm volatile("" : "+v"(Bw[kt].x), "+v"(Bw[kt].y),
                          "+v"(Bw[kt].z), "+v"(Bw[kt].w));

    const float bias = b_hh[w * 16 + c];

    // ---- h0 = 0
    for (int idx = tid; idx < BT * PITCH; idx += NTHR) hbuf[0][idx] = 0;

    // ---- Depth-2 raw-x prefetch: xrA holds t=0, xrB holds t=1.
    const float* xrow = x + (size_t)(b0 + c) * T_STEPS * I_DIM;
    float4 xrA[4], xrB[4];
    {
        const float* p0 = xrow;
        xrA[0] = *(const float4*)(p0 +      q * 8);
        xrA[1] = *(const float4*)(p0 +      q * 8 + 4);
        xrA[2] = *(const float4*)(p0 + 32 + q * 8);
        xrA[3] = *(const float4*)(p0 + 32 + q * 8 + 4);
        const float* p1 = xrow + I_DIM;
        xrB[0] = *(const float4*)(p1 +      q * 8);
        xrB[1] = *(const float4*)(p1 +      q * 8 + 4);
        xrB[2] = *(const float4*)(p1 + 32 + q * 8);
        xrB[3] = *(const float4*)(p1 + 32 + q * 8 + 4);
    }
    __syncthreads();   // once, outside the loop: full drain is fine here

    #pragma unroll 1
    for (int t = 0; t < T_STEPS; t += 2) {
        RNN_STEP(t,     xrA)
        RNN_STEP(t + 1, xrB)
    }

    // ---- Epilogue: out[b0+m][o] = W_ph[o] . h_T + b_ph[o]. Final h in hbuf[0].
    if (tid < BT * O_DIM) {
        const int m = tid / O_DIM;
        const int o = tid % O_DIM;
        float acc = b_ph[o];
        #pragma unroll 4
        for (int k = 0; k < H_DIM; ++k)
            acc = fmaf(W_ph[o * H_DIM + k], bf2f(hbuf[0][m * PITCH + k]), acc);
        out[(size_t)(b0 + m) * O_DIM + o] = acc;
    }
}

extern "C" void kernel_launch(void* const* d_in, const int* in_sizes, int n_in,
                              void* d_out, int out_size, void* d_ws, size_t ws_size,
                              hipStream_t stream) {
    const float* x    = (const float*)d_in[0];
    const float* W_hx = (const float*)d_in[1];
    const float* W_hh = (const float*)d_in[2];
    const float* b_hh = (const float*)d_in[3];
    const float* W_ph = (const float*)d_in[4];
    const float* b_ph = (const float*)d_in[5];
    float* out = (float*)d_out;

    rnn_mfma_kernel<<<1024 / BT, NTHR, 0, stream>>>(x, W_hx, W_hh, b_hh, W_ph, b_ph, out);
}

// Round 8
// 512.691 us; speedup vs baseline: 1.2166x; 1.2166x over previous
//
#include <hip/hip_runtime.h>
#include <math.h>

// VanillaRNN via MFMA: B=1024, T=512, I=64, H=128, O=10, fp32 in/out.
// Block = 16 batch rows (64 blocks), 256 threads = 4 waves (the register-safe
// config: 512-thr blocks made the allocator spill the pinned weights, R7).
// Wall time = 512 x per-step critical path (64 blocks < 256 CUs), so this
// round shortens the post-barrier serial path:
//  - x-part MFMAs + x bf16-convert hoisted into the PREVIOUS step's tail
//    (independent of h) -> post-barrier path = ds_read + 8 h-MFMAs + tanh.
//  - cheap bf16 round ((u+0x8000)>>16, pk2 for pairs) replaces 5-op RNE.
// Kept: LDS-only barrier (no vmcnt drain), depth-2 x prefetch, asm-pinned
// B-frags, PITCH=136 bf16 ping-pong h, 12 MFMAs/wave/step.

#define T_STEPS 512
#define I_DIM   64
#define H_DIM   128
#define O_DIM   10
#define BT      16            // batch rows per block
#define PITCH   136           // bf16 elements per h row

typedef short  bf16x8 __attribute__((ext_vector_type(8)));
typedef float  f32x4  __attribute__((ext_vector_type(4)));

#define MFMA(A, Bi, C) __builtin_amdgcn_mfma_f32_16x16x32_bf16((A), __builtin_bit_cast(bf16x8, (Bi)), (C), 0, 0, 0)

static __device__ inline short f2bf(float f) {               // full RNE (preload only)
    union { float f; unsigned u; } v; v.f = f;
    unsigned r = v.u + 0x7FFFu + ((v.u >> 16) & 1u);
    return (short)(r >> 16);
}
static __device__ inline unsigned rbf(float f) {             // fast round (2 ops)
    return (__builtin_bit_cast(unsigned, f) + 0x8000u) >> 16;
}
static __device__ inline int pk2(float a, float b) {         // fast packed round
    unsigned ua = __builtin_bit_cast(unsigned, a);
    unsigned ub = __builtin_bit_cast(unsigned, b);
    return (int)(((ua + 0x8000u) >> 16) | ((ub + 0x8000u) & 0xFFFF0000u));
}
static __device__ inline float bf2f(short s) {
    union { unsigned u; float f; } v; v.u = ((unsigned)(unsigned short)s) << 16;
    return v.f;
}

// Barrier that does NOT drain vmcnt: h handoff only needs LDS ops complete.
static __device__ inline void lds_barrier() {
    asm volatile("s_waitcnt lgkmcnt(0)\n\ts_barrier" ::: "memory");
}

// One step. Entry: Cx* hold the x-part of THIS step (computed last tail).
// Body: h-MFMAs seeded with Cx, tanh, write h_{t+1}. Tail: convert XR
// (= x of NEXT step), prefetch x at time TN into XR, compute next Cx.
#define RNN_STEP(P, XR, TN)                                                     \
    {                                                                           \
        const short* hb = hbuf[P] + c * PITCH + q * 8;                          \
        bf16x8 Ah0 = *(const bf16x8*)(hb +  0);                                 \
        bf16x8 Ah1 = *(const bf16x8*)(hb + 32);                                 \
        bf16x8 Ah2 = *(const bf16x8*)(hb + 64);                                 \
        bf16x8 Ah3 = *(const bf16x8*)(hb + 96);                                 \
        f32x4 Ca0 = Cxa0, Cb0 = Cxb0, Ca1 = Cxa1, Cb1 = Cxb1;                   \
        Ca0 = MFMA(Ah0, Bw[0][0], Ca0); Ca1 = MFMA(Ah0, Bw[1][0], Ca1);         \
        Cb0 = MFMA(Ah1, Bw[0][1], Cb0); Cb1 = MFMA(Ah1, Bw[1][1], Cb1);         \
        Ca0 = MFMA(Ah2, Bw[0][2], Ca0); Ca1 = MFMA(Ah2, Bw[1][2], Ca1);         \
        Cb0 = MFMA(Ah3, Bw[0][3], Cb0); Cb1 = MFMA(Ah3, Bw[1][3], Cb1);         \
        const f32x4 C0 = Ca0 + Cb0;                                             \
        const f32x4 C1 = Ca1 + Cb1;                                             \
        short* hw = hbuf[1 - (P)];                                              \
        _Pragma("unroll")                                                       \
        for (int r = 0; r < 4; ++r) {                                           \
            const int m = q * 4 + r;                                            \
            float s0 = C0[r] + bias0, s1 = C1[r] + bias1;                       \
            float e0 = __builtin_amdgcn_exp2f(s0 * 2.885390081777926825f);      \
            float e1 = __builtin_amdgcn_exp2f(s1 * 2.885390081777926825f);      \
            float h0 = fmaf(-2.0f, __builtin_amdgcn_rcpf(e0 + 1.0f), 1.0f);     \
            float h1 = fmaf(-2.0f, __builtin_amdgcn_rcpf(e1 + 1.0f), 1.0f);     \
            hw[m * PITCH + w * 32 + c]      = (short)rbf(h0);                   \
            hw[m * PITCH + w * 32 + 16 + c] = (short)rbf(h1);                   \
        }                                                                       \
        /* ---- tail: x-part of the NEXT step (independent of h, pre-barrier) */ \
        {                                                                       \
            int4 axi0, axi1;                                                    \
            axi0.x = pk2(XR[0].x, XR[0].y); axi0.y = pk2(XR[0].z, XR[0].w);     \
            axi0.z = pk2(XR[1].x, XR[1].y); axi0.w = pk2(XR[1].z, XR[1].w);     \
            axi1.x = pk2(XR[2].x, XR[2].y); axi1.y = pk2(XR[2].z, XR[2].w);     \
            axi1.z = pk2(XR[3].x, XR[3].y); axi1.w = pk2(XR[3].z, XR[3].w);     \
            const int tn = ((TN) < T_STEPS) ? (TN) : (T_STEPS - 1);             \
            const float* pn = xrow + (size_t)tn * I_DIM;                        \
            XR[0] = *(const float4*)(pn +      q * 8);                          \
            XR[1] = *(const float4*)(pn +      q * 8 + 4);                      \
            XR[2] = *(const float4*)(pn + 32 + q * 8);                          \
            XR[3] = *(const float4*)(pn + 32 + q * 8 + 4);                      \
            bf16x8 Ax0 = __builtin_bit_cast(bf16x8, axi0);                      \
            bf16x8 Ax1 = __builtin_bit_cast(bf16x8, axi1);                      \
            const f32x4 Z = {0.f, 0.f, 0.f, 0.f};                               \
            Cxa0 = MFMA(Ax0, Bw[0][4], Z);                                      \
            Cxb0 = MFMA(Ax1, Bw[0][5], Z);                                      \
            Cxa1 = MFMA(Ax0, Bw[1][4], Z);                                      \
            Cxb1 = MFMA(Ax1, Bw[1][5], Z);                                      \
        }                                                                       \
        lds_barrier();                                                          \
    }

__global__ __launch_bounds__(256)
__attribute__((amdgpu_waves_per_eu(1, 2)))
void rnn_mfma_kernel(
    const float* __restrict__ x,      // [B, T, I]
    const float* __restrict__ W_hx,   // [H, I]
    const float* __restrict__ W_hh,   // [H, H]
    const float* __restrict__ b_hh,   // [H]
    const float* __restrict__ W_ph,   // [O, H]
    const float* __restrict__ b_ph,   // [O]
    float* __restrict__ out)          // [B, O]
{
    const int b0   = blockIdx.x * BT;
    const int tid  = threadIdx.x;
    const int w    = tid >> 6;        // wave 0..3 -> N cols [32w, 32w+32)
    const int lane = tid & 63;
    const int c    = lane & 15;
    const int q    = lane >> 4;

    __shared__ short hbuf[2][BT * PITCH];   // bf16 h, ping-pong

    // ---- Preload W_cat^T B-fragments: Bw[nt][kt], kt 0..3 = W_hh, 4..5 = W_hx.
    int4 Bw[2][6];
    #pragma unroll
    for (int nt = 0; nt < 2; ++nt) {
        const int n = w * 32 + nt * 16 + c;
        #pragma unroll
        for (int kt = 0; kt < 6; ++kt) {
            const float* src = (kt < 4) ? (W_hh + n * H_DIM + kt * 32 + q * 8)
                                        : (W_hx + n * I_DIM + (kt - 4) * 32 + q * 8);
            short e[8];
            #pragma unroll
            for (int j = 0; j < 8; ++j) e[j] = f2bf(src[j]);
            Bw[nt][kt].x = ((int)(unsigned short)e[0]) | ((int)(unsigned short)e[1] << 16);
            Bw[nt][kt].y = ((int)(unsigned short)e[2]) | ((int)(unsigned short)e[3] << 16);
            Bw[nt][kt].z = ((int)(unsigned short)e[4]) | ((int)(unsigned short)e[5] << 16);
            Bw[nt][kt].w = ((int)(unsigned short)e[6]) | ((int)(unsigned short)e[7] << 16);
        }
    }
    #pragma unroll
    for (int nt = 0; nt < 2; ++nt)
        #pragma unroll
        for (int kt = 0; kt < 6; ++kt)
            asm volatile("" : "+v"(Bw[nt][kt].x), "+v"(Bw[nt][kt].y),
                              "+v"(Bw[nt][kt].z), "+v"(Bw[nt][kt].w));

    const float bias0 = b_hh[w * 32 + c];
    const float bias1 = b_hh[w * 32 + 16 + c];

    // ---- h0 = 0
    for (int idx = tid; idx < BT * PITCH; idx += 256) hbuf[0][idx] = 0;

    // ---- Depth-2 raw-x prefetch: xrA <- x_0, xrB <- x_1.
    const float* xrow = x + (size_t)(b0 + c) * T_STEPS * I_DIM;
    float4 xrA[4], xrB[4];
    {
        const float* p0 = xrow;
        xrA[0] = *(const float4*)(p0 +      q * 8);
        xrA[1] = *(const float4*)(p0 +      q * 8 + 4);
        xrA[2] = *(const float4*)(p0 + 32 + q * 8);
        xrA[3] = *(const float4*)(p0 + 32 + q * 8 + 4);
        const float* p1 = xrow + I_DIM;
        xrB[0] = *(const float4*)(p1 +      q * 8);
        xrB[1] = *(const float4*)(p1 +      q * 8 + 4);
        xrB[2] = *(const float4*)(p1 + 32 + q * 8);
        xrB[3] = *(const float4*)(p1 + 32 + q * 8 + 4);
    }

    // ---- Pre-loop: Cx for step 0 from xrA (= x_0); reissue xrA <- x_2.
    f32x4 Cxa0, Cxb0, Cxa1, Cxb1;
    {
        int4 axi0, axi1;
        axi0.x = pk2(xrA[0].x, xrA[0].y); axi0.y = pk2(xrA[0].z, xrA[0].w);
        axi0.z = pk2(xrA[1].x, xrA[1].y); axi0.w = pk2(xrA[1].z, xrA[1].w);
        axi1.x = pk2(xrA[2].x, xrA[2].y); axi1.y = pk2(xrA[2].z, xrA[2].w);
        axi1.z = pk2(xrA[3].x, xrA[3].y); axi1.w = pk2(xrA[3].z, xrA[3].w);
        const float* p2 = xrow + 2 * I_DIM;
        xrA[0] = *(const float4*)(p2 +      q * 8);
        xrA[1] = *(const float4*)(p2 +      q * 8 + 4);
        xrA[2] = *(const float4*)(p2 + 32 + q * 8);
        xrA[3] = *(const float4*)(p2 + 32 + q * 8 + 4);
        bf16x8 Ax0 = __builtin_bit_cast(bf16x8, axi0);
        bf16x8 Ax1 = __builtin_bit_cast(bf16x8, axi1);
        const f32x4 Z = {0.f, 0.f, 0.f, 0.f};
        Cxa0 = MFMA(Ax0, Bw[0][4], Z);
        Cxb0 = MFMA(Ax1, Bw[0][5], Z);
        Cxa1 = MFMA(Ax0, Bw[1][4], Z);
        Cxb1 = MFMA(Ax1, Bw[1][5], Z);
    }
    __syncthreads();   // once, outside the loop

    #pragma unroll 1
    for (int t = 0; t < T_STEPS; t += 2) {
        RNN_STEP(0, xrB, t + 3)   // step t:   uses Cx(x_t),   tail preps x_{t+1}
        RNN_STEP(1, xrA, t + 4)   // step t+1: uses Cx(x_{t+1}), tail preps x_{t+2}
    }

    // ---- Epilogue: final h_512 sits in hbuf[0].
    if (tid < BT * O_DIM) {
        const int m = tid / O_DIM;
        const int o = tid % O_DIM;
        float acc = b_ph[o];
        #pragma unroll 4
        for (int k = 0; k < H_DIM; ++k)
            acc = fmaf(W_ph[o * H_DIM + k], bf2f(hbuf[0][m * PITCH + k]), acc);
        out[(size_t)(b0 + m) * O_DIM + o] = acc;
    }
}

extern "C" void kernel_launch(void* const* d_in, const int* in_sizes, int n_in,
                              void* d_out, int out_size, void* d_ws, size_t ws_size,
                              hipStream_t stream) {
    const float* x    = (const float*)d_in[0];
    const float* W_hx = (const float*)d_in[1];
    const float* W_hh = (const float*)d_in[2];
    const float* b_hh = (const float*)d_in[3];
    const float* W_ph = (const float*)d_in[4];
    const float* b_ph = (const float*)d_in[5];
    float* out = (float*)d_out;

    rnn_mfma_kernel<<<1024 / BT, 256, 0, stream>>>(x, W_hx, W_hh, b_hh, W_ph, b_ph, out);
}